// Round 5
// baseline (400.006 us; speedup 1.0000x reference)
//
#include <hip/hip_runtime.h>

// PositionEnhancedLoss: f32 L1 loss split into 96x96 patch vs rest, weighted 0.5/0.5.
// x,y: [64,3,512,512] f32. position: [64,2] int64 (rows, cols). Output: 1 f32 scalar.
//
// R5: decisive ILP test. hipcc collapsed every source-level load batch
// (VGPR stuck at 48, R2-R4 all ~2.6-2.9 TB/s delivered). Force 16 outstanding
// loads/wave with inline-asm global_load_dwordx4 (saddr + 32-bit voffset) and
// counted s_waitcnt vmcnt(N) consumption (sched_barrier(0) after each wait,
// per learn_hip rule #18).

#define IMG     512
#define HALF    48
#define B_DIM   64
#define NELEM   (64u * 3u * 512u * 512u)     // 50331648
#define NV4     (NELEM / 4u)                 // 12582912 float4s
#define THREADS 256
#define BLOCKS  2048
#define STRIDE  (BLOCKS * THREADS)           // 524288 float4s = 8 MiB
#define ITERS   (NV4 / STRIDE)               // 24, exact
#define UNROLL  8                            // pairs per batch -> 16 loads in flight
#define OUTER   (ITERS / UNROLL)             // 3
#define IMG_V4  196608u                      // 3*512*512/4, float4s per image

typedef float f32x4 __attribute__((ext_vector_type(4)));

__device__ inline void crop_dim(int d, int& top, int& bot) {
    int t = d - HALF;
    int tr = max(-t, 0);
    t = max(t, 0);
    int b = d + HALF;
    int br = max(b - (IMG - 1), 0);
    b = min(b, IMG - 1);
    top = t - br;      // window [top, bot), width 96
    bot = b + tr;
}

// Decode position (int32 or int64 layout) -> 64 windows in d_ws.
__global__ void pel_setup(const int* __restrict__ pos32, int4* wins) {
    __shared__ int is64_s;
    const int t = threadIdx.x;
    if (t == 0) {
        int allzero = 1;
        for (int i = 1; i < 2 * B_DIM; i += 2) allzero &= (pos32[i] == 0);
        is64_s = allzero;
    }
    __syncthreads();
    if (t < B_DIM) {
        int r, c;
        if (is64_s) {
            const long long* p64 = (const long long*)pos32;
            r = (int)p64[2 * t];
            c = (int)p64[2 * t + 1];
        } else {
            r = pos32[2 * t];
            c = pos32[2 * t + 1];
        }
        int ty, by, tx, bx;
        crop_dim(r, ty, by);
        crop_dim(c, tx, bx);
        wins[t] = make_int4(ty, by, tx, bx);
    }
}

// Raw load: dst <- mem[sbase + voff]. asm volatile => cannot be collapsed/moved.
#define GLOAD(dst, voff, sbase) \
    asm volatile("global_load_dwordx4 %0, %1, %2" \
                 : "=v"(dst) : "v"(voff), "s"(sbase) : "memory")

// Counted wait + scheduling fence (rule #18: compiler hoists reg-only uses past
// an asm waitcnt unless fenced).
#define WAIT_VMCNT(n) \
    asm volatile("s_waitcnt vmcnt(" #n ")" ::: "memory"); \
    __builtin_amdgcn_sched_barrier(0)

__global__ __launch_bounds__(THREADS) void pel_main(const float4* __restrict__ x,
                                                    const float4* __restrict__ y,
                                                    const int4* __restrict__ wins,
                                                    float2* __restrict__ partials) {
    __shared__ int4 s_wins[B_DIM];
    if (threadIdx.x < B_DIM) s_wins[threadIdx.x] = wins[threadIdx.x];
    __syncthreads();

    const unsigned base = blockIdx.x * THREADS + threadIdx.x;
    const unsigned long long bx = (unsigned long long)x;
    const unsigned long long by = (unsigned long long)y;
    float psum = 0.0f, tsum = 0.0f;

    #pragma unroll 1
    for (int o = 0; o < OUTER; ++o) {
        f32x4 xv0, xv1, xv2, xv3, xv4, xv5, xv6, xv7;
        f32x4 yv0, yv1, yv2, yv3, yv4, yv5, yv6, yv7;
        const unsigned i0 = base + (unsigned)(o * UNROLL) * STRIDE;
        // byte voffsets (buffer is 201 MiB, fits 32-bit; bit31 never set)
        const unsigned v0 = (i0 + 0u * STRIDE) * 16u;
        const unsigned v1 = (i0 + 1u * STRIDE) * 16u;
        const unsigned v2 = (i0 + 2u * STRIDE) * 16u;
        const unsigned v3 = (i0 + 3u * STRIDE) * 16u;
        const unsigned v4 = (i0 + 4u * STRIDE) * 16u;
        const unsigned v5 = (i0 + 5u * STRIDE) * 16u;
        const unsigned v6 = (i0 + 6u * STRIDE) * 16u;
        const unsigned v7 = (i0 + 7u * STRIDE) * 16u;
        // Issue 16 loads, in consumption order (x_u then y_u).
        GLOAD(xv0, v0, bx); GLOAD(yv0, v0, by);
        GLOAD(xv1, v1, bx); GLOAD(yv1, v1, by);
        GLOAD(xv2, v2, bx); GLOAD(yv2, v2, by);
        GLOAD(xv3, v3, bx); GLOAD(yv3, v3, by);
        GLOAD(xv4, v4, bx); GLOAD(yv4, v4, by);
        GLOAD(xv5, v5, bx); GLOAD(yv5, v5, by);
        GLOAD(xv6, v6, bx); GLOAD(yv6, v6, by);
        GLOAD(xv7, v7, bx); GLOAD(yv7, v7, by);
        __builtin_amdgcn_sched_barrier(0);

        #define CONSUME(u, xv, yv)                                             \
        {                                                                      \
            const unsigned i = i0 + (unsigned)(u) * STRIDE;                    \
            const float a0 = fabsf(xv.x - yv.x);                               \
            const float a1 = fabsf(xv.y - yv.y);                               \
            const float a2 = fabsf(xv.z - yv.z);                               \
            const float a3 = fabsf(xv.w - yv.w);                               \
            tsum += (a0 + a1) + (a2 + a3);                                     \
            const unsigned b = i / IMG_V4;                                     \
            const int r = (int)((i >> 7) & 511u);                              \
            const int c = (int)((i & 127u) << 2);                              \
            const int4 w = s_wins[b];                                          \
            if ((unsigned)(r - w.x) < 96u) {                                   \
                float p = 0.0f;                                                \
                p += ((unsigned)(c     - w.z) < 96u) ? a0 : 0.0f;              \
                p += ((unsigned)(c + 1 - w.z) < 96u) ? a1 : 0.0f;              \
                p += ((unsigned)(c + 2 - w.z) < 96u) ? a2 : 0.0f;              \
                p += ((unsigned)(c + 3 - w.z) < 96u) ? a3 : 0.0f;              \
                psum += p;                                                     \
            }                                                                  \
        }

        WAIT_VMCNT(14); CONSUME(0, xv0, yv0);
        WAIT_VMCNT(12); CONSUME(1, xv1, yv1);
        WAIT_VMCNT(10); CONSUME(2, xv2, yv2);
        WAIT_VMCNT(8);  CONSUME(3, xv3, yv3);
        WAIT_VMCNT(6);  CONSUME(4, xv4, yv4);
        WAIT_VMCNT(4);  CONSUME(5, xv5, yv5);
        WAIT_VMCNT(2);  CONSUME(6, xv6, yv6);
        WAIT_VMCNT(0);  CONSUME(7, xv7, yv7);
        #undef CONSUME
    }

    // wave-64 butterfly reduce
    #pragma unroll
    for (int off = 32; off > 0; off >>= 1) {
        psum += __shfl_down(psum, off);
        tsum += __shfl_down(tsum, off);
    }
    __shared__ float sp[4], st[4];
    const int wave = threadIdx.x >> 6;
    if ((threadIdx.x & 63) == 0) { sp[wave] = psum; st[wave] = tsum; }
    __syncthreads();
    if (threadIdx.x == 0) {
        partials[blockIdx.x] = make_float2((sp[0] + sp[1]) + (sp[2] + sp[3]),
                                           (st[0] + st[1]) + (st[2] + st[3]));
    }
}

__global__ __launch_bounds__(256) void pel_final(const float2* __restrict__ partials,
                                                 float* __restrict__ out) {
    double psum = 0.0, tsum = 0.0;
    for (int i = threadIdx.x; i < BLOCKS; i += 256) {
        const float2 v = partials[i];
        psum += (double)v.x;
        tsum += (double)v.y;
    }
    #pragma unroll
    for (int off = 32; off > 0; off >>= 1) {
        psum += __shfl_down(psum, off);
        tsum += __shfl_down(tsum, off);
    }
    __shared__ double sp[4], st[4];
    const int wave = threadIdx.x >> 6;
    if ((threadIdx.x & 63) == 0) { sp[wave] = psum; st[wave] = tsum; }
    __syncthreads();
    if (threadIdx.x == 0) {
        const double patch_sum = (sp[0] + sp[1]) + (sp[2] + sp[3]);
        const double total_sum = (st[0] + st[1]) + (st[2] + st[3]);
        const double rest_sum = total_sum - patch_sum;
        const double patch_numel = 64.0 * 3.0 * 96.0 * 96.0;      // 1769472
        const double rest_numel = (double)NELEM - patch_numel;
        out[0] = (float)((rest_sum / rest_numel) * 0.5 + 0.5 * (patch_sum / patch_numel));
    }
}

extern "C" void kernel_launch(void* const* d_in, const int* in_sizes, int n_in,
                              void* d_out, int out_size, void* d_ws, size_t ws_size,
                              hipStream_t stream) {
    const float* x = (const float*)d_in[0];
    const float* y = (const float*)d_in[1];
    const int*   pos = (const int*)d_in[2];
    int4*   wins     = (int4*)d_ws;                       // 64 * 16 B
    float2* partials = (float2*)((char*)d_ws + 1024);     // 2048 * 8 B

    pel_setup<<<1, 64, 0, stream>>>(pos, wins);
    pel_main<<<BLOCKS, THREADS, 0, stream>>>((const float4*)x, (const float4*)y, wins, partials);
    pel_final<<<1, 256, 0, stream>>>(partials, (float*)d_out);
}